// Round 1
// baseline (460.691 us; speedup 1.0000x reference)
//
#include <hip/hip_runtime.h>

#define TT  1024
#define NH  16
#define DD  128
#define WIN 256

// Cross-head projection for one band column `col` (s = s0+col).
// ret[n] = inp[n] + sum_m inp[m]*W[m][n]
//        + sum_i ( (sum_m inp[m]*qw1[m,i]) * qw2[n,i] + (sum_m inp[m]*kw1[s,m,i]) * kw2[s,n,i] )
//        + inp[n]*(qdd[n] + kdd[s,n])
__device__ __forceinline__ void proj_column(
    int col, int L, int bts,
    float (*sL)[WIN + 1],
    const float* sW, const float* sQw1, const float* sQw2, const float* sQdd,
    const float* __restrict__ kw1, const float* __restrict__ kw2,
    const float* __restrict__ kdd)
{
  if (col >= L) return;
  float inp[16], ret[16];
#pragma unroll
  for (int m = 0; m < 16; ++m) inp[m] = sL[m][col];
#pragma unroll
  for (int n = 0; n < 16; ++n) ret[n] = inp[n];
#pragma unroll
  for (int m = 0; m < 16; ++m) {
    const float im = inp[m];
#pragma unroll
    for (int n = 0; n < 16; ++n) ret[n] = fmaf(im, sW[m * 16 + n], ret[n]);
  }
  const float* kw1p = kw1 + bts * 32;
  const float* kw2p = kw2 + bts * 32;
#pragma unroll
  for (int i = 0; i < 2; ++i) {
    float hq = 0.f, hk = 0.f;
#pragma unroll
    for (int m = 0; m < 16; ++m) {
      hq = fmaf(inp[m], sQw1[m * 2 + i], hq);
      hk = fmaf(inp[m], kw1p[m * 2 + i], hk);
    }
#pragma unroll
    for (int n = 0; n < 16; ++n)
      ret[n] += hq * sQw2[n * 2 + i] + hk * kw2p[n * 2 + i];
  }
  const float* kddp = kdd + bts * 16;
#pragma unroll
  for (int n = 0; n < 16; ++n)
    ret[n] = fmaf(inp[n], sQdd[n] + kddp[n], ret[n]);
#pragma unroll
  for (int n = 0; n < 16; ++n) sL[n][col] = ret[n];
}

__global__ __launch_bounds__(256)
void attn_win_kernel(const float* __restrict__ q, const float* __restrict__ k,
                     const float* __restrict__ v,
                     const float* __restrict__ w_pre, const float* __restrict__ w_post,
                     const float* __restrict__ qw1_pre, const float* __restrict__ qw2_pre,
                     const float* __restrict__ kw1_pre, const float* __restrict__ kw2_pre,
                     const float* __restrict__ qw1_post, const float* __restrict__ qw2_post,
                     const float* __restrict__ kw1_post, const float* __restrict__ kw2_post,
                     const float* __restrict__ qdd_pre, const float* __restrict__ kdd_pre,
                     const float* __restrict__ qdd_post, const float* __restrict__ kdd_post,
                     float* __restrict__ out)
{
  const int bt  = blockIdx.x;
  const int b   = bt >> 10;          // T = 1024
  const int t   = bt & (TT - 1);
  const int tid = threadIdx.x;
  const int s0  = (t > WIN - 1) ? t - (WIN - 1) : 0;  // band: s in [s0, t]
  const int L   = t - s0 + 1;                         // <= 256

  __shared__ float sL[NH][WIN + 1];     // padded stride -> conflict-free
  __shared__ float sWpre[256], sWpost[256];
  __shared__ float sQw1pre[32], sQw2pre[32], sQw1post[32], sQw2post[32];
  __shared__ float sQddpre[16], sQddpost[16];

  const int btq = b * TT + t;
  sWpre[tid]  = w_pre[tid];
  sWpost[tid] = w_post[tid];
  if (tid < 32) {
    sQw1pre[tid]  = qw1_pre [btq * 32 + tid];
    sQw2pre[tid]  = qw2_pre [btq * 32 + tid];
    sQw1post[tid] = qw1_post[btq * 32 + tid];
    sQw2post[tid] = qw2_post[btq * 32 + tid];
  }
  if (tid < 16) {
    sQddpre[tid]  = qdd_pre [btq * 16 + tid];
    sQddpost[tid] = qdd_post[btq * 16 + tid];
  }

  const int g   = tid >> 4;   // head 0..15 (group of 16 lanes)
  const int lid = tid & 15;

  // q fragment for head g, pre-scaled by 1/sqrt(D)
  const float scale = 0.08838834764831845f;
  float qr[8];
  {
    const float* qp = q + (btq * NH + g) * DD + lid * 8;
    float4 a = *(const float4*)qp;
    float4 c = *(const float4*)(qp + 4);
    qr[0] = a.x * scale; qr[1] = a.y * scale; qr[2] = a.z * scale; qr[3] = a.w * scale;
    qr[4] = c.x * scale; qr[5] = c.y * scale; qr[6] = c.z * scale; qr[7] = c.w * scale;
  }

  // ---- QK^T over the band: group g computes logits for head g ----
  {
    const float* kp0 = k + ((b * TT + s0) * NH + g) * DD + lid * 8;
#pragma unroll 4
    for (int ss = 0; ss < L; ++ss) {
      const float* kp = kp0 + ss * (NH * DD);
      float4 a = *(const float4*)kp;
      float4 c = *(const float4*)(kp + 4);
      float d = qr[0]*a.x + qr[1]*a.y + qr[2]*a.z + qr[3]*a.w
              + qr[4]*c.x + qr[5]*c.y + qr[6]*c.z + qr[7]*c.w;
      d += __shfl_xor(d, 1, 16);
      d += __shfl_xor(d, 2, 16);
      d += __shfl_xor(d, 4, 16);
      d += __shfl_xor(d, 8, 16);
      if (lid == 0) sL[g][ss] = d;
    }
  }
  __syncthreads();

  // ---- pre-softmax cross-head projection (thread = band column) ----
  proj_column(tid, L, b * TT + s0 + tid, sL, sWpre, sQw1pre, sQw2pre, sQddpre,
              kw1_pre, kw2_pre, kdd_pre);
  __syncthreads();

  // ---- softmax over the band (masked cols are exact zeros -> band-only is exact) ----
  {
    float mx = -3.0e38f;
    for (int ss = lid; ss < L; ss += 16) mx = fmaxf(mx, sL[g][ss]);
    mx = fmaxf(mx, __shfl_xor(mx, 1, 16));
    mx = fmaxf(mx, __shfl_xor(mx, 2, 16));
    mx = fmaxf(mx, __shfl_xor(mx, 4, 16));
    mx = fmaxf(mx, __shfl_xor(mx, 8, 16));
    float sum = 0.f;
    for (int ss = lid; ss < L; ss += 16) {
      float e = __expf(sL[g][ss] - mx);
      sL[g][ss] = e;
      sum += e;
    }
    sum += __shfl_xor(sum, 1, 16);
    sum += __shfl_xor(sum, 2, 16);
    sum += __shfl_xor(sum, 4, 16);
    sum += __shfl_xor(sum, 8, 16);
    const float rinv = 1.f / sum;
    for (int ss = lid; ss < L; ss += 16) sL[g][ss] *= rinv;
  }
  __syncthreads();

  // ---- post-softmax cross-head projection ----
  proj_column(tid, L, b * TT + s0 + tid, sL, sWpost, sQw1post, sQw2post, sQddpost,
              kw1_post, kw2_post, kdd_post);
  __syncthreads();

  // ---- PV: thread (head g, dims lid*8..lid*8+7) ----
  {
    float acc[8] = {0.f,0.f,0.f,0.f,0.f,0.f,0.f,0.f};
    const float* vp = v + ((b * TT + s0) * NH + g) * DD + lid * 8;
    for (int ss = 0; ss < L; ++ss, vp += NH * DD) {
      const float p = sL[g][ss];
      float4 a = *(const float4*)vp;
      float4 c = *(const float4*)(vp + 4);
      acc[0] = fmaf(p, a.x, acc[0]);
      acc[1] = fmaf(p, a.y, acc[1]);
      acc[2] = fmaf(p, a.z, acc[2]);
      acc[3] = fmaf(p, a.w, acc[3]);
      acc[4] = fmaf(p, c.x, acc[4]);
      acc[5] = fmaf(p, c.y, acc[5]);
      acc[6] = fmaf(p, c.z, acc[6]);
      acc[7] = fmaf(p, c.w, acc[7]);
    }
    float* op = out + (btq * NH + g) * DD + lid * 8;
    *(float4*)(op)     = make_float4(acc[0], acc[1], acc[2], acc[3]);
    *(float4*)(op + 4) = make_float4(acc[4], acc[5], acc[6], acc[7]);
  }
}

extern "C" void kernel_launch(void* const* d_in, const int* in_sizes, int n_in,
                              void* d_out, int out_size, void* d_ws, size_t ws_size,
                              hipStream_t stream) {
  const float* q        = (const float*)d_in[0];
  const float* k        = (const float*)d_in[1];
  const float* v        = (const float*)d_in[2];
  const float* w_pre    = (const float*)d_in[3];
  const float* w_post   = (const float*)d_in[4];
  const float* qw1_pre  = (const float*)d_in[5];
  const float* qw2_pre  = (const float*)d_in[6];
  const float* kw1_pre  = (const float*)d_in[7];
  const float* kw2_pre  = (const float*)d_in[8];
  const float* qw1_post = (const float*)d_in[9];
  const float* qw2_post = (const float*)d_in[10];
  const float* kw1_post = (const float*)d_in[11];
  const float* kw2_post = (const float*)d_in[12];
  const float* qdd_pre  = (const float*)d_in[13];
  const float* kdd_pre  = (const float*)d_in[14];
  const float* qdd_post = (const float*)d_in[15];
  const float* kdd_post = (const float*)d_in[16];
  float* out = (float*)d_out;

  dim3 grid(2 * TT);   // one block per (b, t)
  dim3 block(256);
  attn_win_kernel<<<grid, block, 0, stream>>>(
      q, k, v, w_pre, w_post,
      qw1_pre, qw2_pre, kw1_pre, kw2_pre,
      qw1_post, qw2_post, kw1_post, kw2_post,
      qdd_pre, kdd_pre, qdd_post, kdd_post, out);
}

// Round 2
// 205.053 us; speedup vs baseline: 2.2467x; 2.2467x over previous
//
#include <hip/hip_runtime.h>

#define TT 1024
#define NH 16
#define DD 128
#define WIN 256
#define TQ 8
#define CS 32
#define WSPITCH 288   // 9 chunks * 32
#define VTP 1032      // padded s-pitch of transposed V
#define SCALE 0.08838834764831845f

typedef float f32x4 __attribute__((ext_vector_type(4)));
typedef short s16x8 __attribute__((ext_vector_type(8)));

__device__ __forceinline__ ushort f2bf(float x) {
  union { float f; unsigned u; } v; v.f = x;
  unsigned r = v.u + 0x7FFFu + ((v.u >> 16) & 1u);
  return (ushort)(r >> 16);
}

// ---------- pre-kernel 1: k fp32 -> bf16 ----------
__global__ __launch_bounds__(256)
void conv_k(const float* __restrict__ k, ushort* __restrict__ kb) {
  long long i = ((long long)blockIdx.x * 256 + threadIdx.x) * 8;
  float4 a = *(const float4*)(k + i);
  float4 c = *(const float4*)(k + i + 4);
  union { ushort u[8]; uint4 v; } pk;
  pk.u[0]=f2bf(a.x); pk.u[1]=f2bf(a.y); pk.u[2]=f2bf(a.z); pk.u[3]=f2bf(a.w);
  pk.u[4]=f2bf(c.x); pk.u[5]=f2bf(c.y); pk.u[6]=f2bf(c.z); pk.u[7]=f2bf(c.w);
  *(uint4*)(kb + i) = pk.v;
}

// ---------- pre-kernel 2: v fp32 [b][s][h][d] -> vT bf16 [b][h][d][s(pitch 1032)] ----------
__global__ __launch_bounds__(256)
void trans_v(const float* __restrict__ v, ushort* __restrict__ vT) {
  int blk = blockIdx.x;
  int st = blk & 31, dt = (blk >> 5) & 3, h = (blk >> 7) & 15, b = blk >> 11;
  __shared__ float tile[32][33];
  int c = threadIdx.x & 31, r4 = threadIdx.x >> 5;  // r4: 0..7
#pragma unroll
  for (int rr = 0; rr < 4; ++rr) {
    int s = st * 32 + r4 + rr * 8;
    tile[r4 + rr * 8][c] = v[((long long)(b * TT + s) * NH + h) * DD + dt * 32 + c];
  }
  __syncthreads();
#pragma unroll
  for (int rr = 0; rr < 4; ++rr) {
    int d = dt * 32 + r4 + rr * 8;
    vT[((long long)(b * NH + h) * DD + d) * VTP + st * 32 + c] = f2bf(tile[c][r4 + rr * 8]);
  }
}

// ---------- main kernel: one block per (b, 8-query tile) ----------
__global__ __launch_bounds__(512, 2)
void attn_main(
    const float* __restrict__ q,
    const float* __restrict__ w_pre,  const float* __restrict__ w_post,
    const float* __restrict__ qw1_pre, const float* __restrict__ qw2_pre,
    const float* __restrict__ kw1_pre, const float* __restrict__ kw2_pre,
    const float* __restrict__ qw1_post, const float* __restrict__ qw2_post,
    const float* __restrict__ kw1_post, const float* __restrict__ kw2_post,
    const float* __restrict__ qdd_pre, const float* __restrict__ kdd_pre,
    const float* __restrict__ qdd_post, const float* __restrict__ kdd_post,
    const ushort* __restrict__ kb, const ushort* __restrict__ vT,
    float* __restrict__ wsLog, float* __restrict__ out)
{
  const int tid = threadIdx.x;
  const int blk = blockIdx.x;
  const int b = blk >> 7, qt = blk & 127;
  const int t0 = qt * TQ;
  const int s0 = (t0 >= WIN) ? (t0 - WIN + 1) : 0;
  const int send = t0 + TQ - 1;
  const int Lb = send - s0 + 1;
  const int nch = (Lb + CS - 1) / CS;

  const int lane = tid & 63, wave = tid >> 6;
  const int sl = tid & 31, qi = (tid >> 5) & 7, nh = tid >> 8;
  const int tq_self = t0 + qi;

  __shared__ float sLog[16 * 8 * 33];
  __shared__ float sLog2[16 * 8 * 33];
  __shared__ float sMq[8 * 16 * 16];
  __shared__ ushort sP[16 * 16 * 48];
  __shared__ float sM[128], sZ[128], sRz[128];

  // ---- Q fragments (A operand, rows=q, 8 contiguous d per lane), pre-scaled ----
  s16x8 qa[2][4];
  {
    int row = lane & 15; if (row > 7) row = 7;     // rows 8-15 duplicate row 7 (ignored)
    int tql = t0 + row;
    int dbase = (lane >> 4) * 8;
#pragma unroll
    for (int hh = 0; hh < 2; ++hh) {
      int h = wave * 2 + hh;
      const float* qp = q + ((long long)(b * TT + tql) * NH + h) * DD + dbase;
#pragma unroll
      for (int kk = 0; kk < 4; ++kk) {
        float4 a = *(const float4*)(qp + kk * 32);
        float4 c = *(const float4*)(qp + kk * 32 + 4);
        union { ushort u[8]; s16x8 v; } pk;
        pk.u[0]=f2bf(a.x*SCALE); pk.u[1]=f2bf(a.y*SCALE); pk.u[2]=f2bf(a.z*SCALE); pk.u[3]=f2bf(a.w*SCALE);
        pk.u[4]=f2bf(c.x*SCALE); pk.u[5]=f2bf(c.y*SCALE); pk.u[6]=f2bf(c.z*SCALE); pk.u[7]=f2bf(c.w*SCALE);
        qa[hh][kk] = pk.v;
      }
    }
  }

  // ---- build combined per-q matrix: Mq = I + W + qw1*qw2^T + diag(qdd) ----
#define BUILD_MQ(W, QW1, QW2, QDD)                                          \
  {                                                                          \
    _Pragma("unroll")                                                        \
    for (int ii = 0; ii < 4; ++ii) {                                         \
      int e = tid * 4 + ii;                                                  \
      int n = e & 15, m = (e >> 4) & 15, qq = e >> 8;                        \
      int btq = b * TT + t0 + qq;                                            \
      const float* p1 = (QW1) + ((long long)btq * 16 + m) * 2;               \
      const float* p2 = (QW2) + ((long long)btq * 16 + n) * 2;               \
      float val = (W)[m * 16 + n] + p1[0] * p2[0] + p1[1] * p2[1];           \
      if (m == n) val += 1.0f + (QDD)[(long long)btq * 16 + n];              \
      sMq[(qq * 16 + m) * 16 + n] = val;                                     \
    }                                                                        \
  }

  if (tid < 128) { sM[tid] = -3.0e38f; sZ[tid] = 0.0f; }
  BUILD_MQ(w_pre, qw1_pre, qw2_pre, qdd_pre);
  __syncthreads();

  // ================= PASS 1: logits + pre-proj + mask + stats =================
  for (int ch = 0; ch < nch; ++ch) {
    // QK^T via MFMA: D[q16 x s16] per (head, s-subtile)
#pragma unroll
    for (int hh = 0; hh < 2; ++hh) {
      int h = wave * 2 + hh;
#pragma unroll
      for (int st2 = 0; st2 < 2; ++st2) {
        int sg = s0 + ch * CS + st2 * 16 + (lane & 15);
        if (sg > TT - 1) sg = TT - 1;
        const ushort* kp = kb + ((long long)(b * TT + sg) * NH + h) * DD + (lane >> 4) * 8;
        f32x4 acc = {0.f, 0.f, 0.f, 0.f};
#pragma unroll
        for (int kk = 0; kk < 4; ++kk)
          acc = __builtin_amdgcn_mfma_f32_16x16x32_bf16(qa[hh][kk], *(const s16x8*)(kp + kk * 32), acc, 0, 0, 0);
        int rbase = (lane >> 4) * 4;
        if (rbase < 8) {
#pragma unroll
          for (int j = 0; j < 4; ++j)
            sLog[(h * 8 + rbase + j) * 33 + st2 * 16 + (lane & 15)] = acc[j];
        }
      }
    }
    __syncthreads();

    // pre-softmax projection: thread = (q, s, n-half)
    {
      int sg = s0 + ch * CS + sl;
      int sgc = (sg > TT - 1) ? TT - 1 : sg;
      long long bts = (long long)(b * TT + sgc);
      float kw1r[32], kw2r[16], kddr[8];
      const float4* p1 = (const float4*)(kw1_pre + bts * 32);
#pragma unroll
      for (int i = 0; i < 8; ++i) ((float4*)kw1r)[i] = p1[i];
      const float4* p2 = (const float4*)(kw2_pre + bts * 32 + nh * 16);
#pragma unroll
      for (int i = 0; i < 4; ++i) ((float4*)kw2r)[i] = p2[i];
      const float4* p3 = (const float4*)(kdd_pre + bts * 16 + nh * 8);
#pragma unroll
      for (int i = 0; i < 2; ++i) ((float4*)kddr)[i] = p3[i];

      float inp[16];
#pragma unroll
      for (int m = 0; m < 16; ++m) inp[m] = sLog[(m * 8 + qi) * 33 + sl];
      float hk0 = 0.f, hk1 = 0.f;
#pragma unroll
      for (int m = 0; m < 16; ++m) {
        hk0 = fmaf(inp[m], kw1r[2 * m], hk0);
        hk1 = fmaf(inp[m], kw1r[2 * m + 1], hk1);
      }
      float ret[8] = {0.f,0.f,0.f,0.f,0.f,0.f,0.f,0.f};
#pragma unroll
      for (int m = 0; m < 16; ++m) {
        f32x4 a = *(const f32x4*)&sMq[(qi * 16 + m) * 16 + nh * 8];
        f32x4 c = *(const f32x4*)&sMq[(qi * 16 + m) * 16 + nh * 8 + 4];
        ret[0] = fmaf(inp[m], a[0], ret[0]); ret[1] = fmaf(inp[m], a[1], ret[1]);
        ret[2] = fmaf(inp[m], a[2], ret[2]); ret[3] = fmaf(inp[m], a[3], ret[3]);
        ret[4] = fmaf(inp[m], c[0], ret[4]); ret[5] = fmaf(inp[m], c[1], ret[5]);
        ret[6] = fmaf(inp[m], c[2], ret[6]); ret[7] = fmaf(inp[m], c[3], ret[7]);
      }
      bool valid = (sg <= tq_self) && (sg >= tq_self - (WIN - 1));
      float* wsp = wsLog + (long long)blk * 36864 + ch * CS + sl;
#pragma unroll
      for (int n = 0; n < 8; ++n) {
        float v2 = fmaf(hk0, kw2r[2 * n], ret[n]);
        v2 = fmaf(hk1, kw2r[2 * n + 1], v2);
        v2 = fmaf(inp[nh * 8 + n], kddr[n], v2);
        v2 = valid ? v2 : -1.0e30f;
        sLog2[((nh * 8 + n) * 8 + qi) * 33 + sl] = v2;
        wsp[((nh * 8 + n) * 8 + qi) * WSPITCH] = v2;
      }
    }
    __syncthreads();

    // running softmax stats per (h,q)
    if (tid < 128) {
      float mold = sM[tid];
      float mx = mold;
      const float* rowp = &sLog2[tid * 33];
#pragma unroll
      for (int s = 0; s < 32; ++s) mx = fmaxf(mx, rowp[s]);
      float zsc = __expf(mold - mx);
      float zs = 0.f;
#pragma unroll
      for (int s = 0; s < 32; ++s) zs += __expf(rowp[s] - mx);
      sZ[tid] = sZ[tid] * zsc + zs;
      sM[tid] = mx;
    }
  }
  __syncthreads();
  if (tid < 128) sRz[tid] = 1.0f / sZ[tid];
  BUILD_MQ(w_post, qw1_post, qw2_post, qdd_post);
  __syncthreads();

  // ================= PASS 2: normalize + post-proj + PV =================
  f32x4 pv[2][8];
#pragma unroll
  for (int hh = 0; hh < 2; ++hh)
#pragma unroll
    for (int dt = 0; dt < 8; ++dt) pv[hh][dt] = (f32x4){0.f, 0.f, 0.f, 0.f};

  for (int ch = 0; ch < nch; ++ch) {
    // reload logits, exp-normalize into sLog (probs)
    {
      int r = tid >> 2, cg = (tid & 3) * 8;
      float mv = sM[r], rz = sRz[r];
      const float* wp = wsLog + (long long)blk * 36864 + r * WSPITCH + ch * CS + cg;
      float4 x = *(const float4*)wp;
      float4 y = *(const float4*)(wp + 4);
      float* dst = &sLog[r * 33 + cg];
      dst[0] = __expf(x.x - mv) * rz; dst[1] = __expf(x.y - mv) * rz;
      dst[2] = __expf(x.z - mv) * rz; dst[3] = __expf(x.w - mv) * rz;
      dst[4] = __expf(y.x - mv) * rz; dst[5] = __expf(y.y - mv) * rz;
      dst[6] = __expf(y.z - mv) * rz; dst[7] = __expf(y.w - mv) * rz;
    }
    __syncthreads();

    // post-softmax projection on probs -> sP (bf16)
    {
      int sg = s0 + ch * CS + sl;
      int sgc = (sg > TT - 1) ? TT - 1 : sg;
      long long bts = (long long)(b * TT + sgc);
      float kw1r[32], kw2r[16], kddr[8];
      const float4* p1 = (const float4*)(kw1_post + bts * 32);
#pragma unroll
      for (int i = 0; i < 8; ++i) ((float4*)kw1r)[i] = p1[i];
      const float4* p2 = (const float4*)(kw2_post + bts * 32 + nh * 16);
#pragma unroll
      for (int i = 0; i < 4; ++i) ((float4*)kw2r)[i] = p2[i];
      const float4* p3 = (const float4*)(kdd_post + bts * 16 + nh * 8);
#pragma unroll
      for (int i = 0; i < 2; ++i) ((float4*)kddr)[i] = p3[i];

      float inp[16];
#pragma unroll
      for (int m = 0; m < 16; ++m) inp[m] = sLog[(m * 8 + qi) * 33 + sl];
      float hk0 = 0.f, hk1 = 0.f;
#pragma unroll
      for (int m = 0; m < 16; ++m) {
        hk0 = fmaf(inp[m], kw1r[2 * m], hk0);
        hk1 = fmaf(inp[m], kw1r[2 * m + 1], hk1);
      }
      float ret[8] = {0.f,0.f,0.f,0.f,0.f,0.f,0.f,0.f};
#pragma unroll
      for (int m = 0; m < 16; ++m) {
        f32x4 a = *(const f32x4*)&sMq[(qi * 16 + m) * 16 + nh * 8];
        f32x4 c = *(const f32x4*)&sMq[(qi * 16 + m) * 16 + nh * 8 + 4];
        ret[0] = fmaf(inp[m], a[0], ret[0]); ret[1] = fmaf(inp[m], a[1], ret[1]);
        ret[2] = fmaf(inp[m], a[2], ret[2]); ret[3] = fmaf(inp[m], a[3], ret[3]);
        ret[4] = fmaf(inp[m], c[0], ret[4]); ret[5] = fmaf(inp[m], c[1], ret[5]);
        ret[6] = fmaf(inp[m], c[2], ret[6]); ret[7] = fmaf(inp[m], c[3], ret[7]);
      }
#pragma unroll
      for (int n = 0; n < 8; ++n) {
        float v2 = fmaf(hk0, kw2r[2 * n], ret[n]);
        v2 = fmaf(hk1, kw2r[2 * n + 1], v2);
        v2 = fmaf(inp[nh * 8 + n], kddr[n], v2);
        sP[((nh * 8 + n) * 16 + qi) * 48 + sl] = f2bf(v2);
      }
    }
    __syncthreads();

    // PV via MFMA: D[q16 x d16] += P'[q x s32] * V[s32 x d16]
#pragma unroll
    for (int hh = 0; hh < 2; ++hh) {
      int h = wave * 2 + hh;
      s16x8 pa = *(const s16x8*)&sP[(h * 16 + (lane & 15)) * 48 + (lane >> 4) * 8];
      int sb = ch * CS + (lane >> 4) * 8;
      int sbase = (sb >= Lb) ? s0 : (s0 + sb);   // all-masked group -> P'=0, any in-bounds addr
      const ushort* vp = vT + ((long long)(b * NH + h) * DD) * VTP + sbase;
#pragma unroll
      for (int dt = 0; dt < 8; ++dt) {
        int d = dt * 16 + (lane & 15);
        s16x8 vb = *(const s16x8*)(vp + (long long)d * VTP);
        pv[hh][dt] = __builtin_amdgcn_mfma_f32_16x16x32_bf16(pa, vb, pv[hh][dt], 0, 0, 0);
      }
    }
  }

  // ---- epilogue: write out [b][t][h][d] fp32 ----
  {
    int rbase = (lane >> 4) * 4;
    if (rbase < 8) {
#pragma unroll
      for (int hh = 0; hh < 2; ++hh) {
        int h = wave * 2 + hh;
#pragma unroll
        for (int dt = 0; dt < 8; ++dt) {
          int d = dt * 16 + (lane & 15);
#pragma unroll
          for (int j = 0; j < 4; ++j)
            out[((long long)(b * TT + t0 + rbase + j) * NH + h) * DD + d] = pv[hh][dt][j];
        }
      }
    }
  }
}

extern "C" void kernel_launch(void* const* d_in, const int* in_sizes, int n_in,
                              void* d_out, int out_size, void* d_ws, size_t ws_size,
                              hipStream_t stream) {
  const float* q        = (const float*)d_in[0];
  const float* k        = (const float*)d_in[1];
  const float* v        = (const float*)d_in[2];
  const float* w_pre    = (const float*)d_in[3];
  const float* w_post   = (const float*)d_in[4];
  const float* qw1_pre  = (const float*)d_in[5];
  const float* qw2_pre  = (const float*)d_in[6];
  const float* kw1_pre  = (const float*)d_in[7];
  const float* kw2_pre  = (const float*)d_in[8];
  const float* qw1_post = (const float*)d_in[9];
  const float* qw2_post = (const float*)d_in[10];
  const float* kw1_post = (const float*)d_in[11];
  const float* kw2_post = (const float*)d_in[12];
  const float* qdd_pre  = (const float*)d_in[13];
  const float* kdd_pre  = (const float*)d_in[14];
  const float* qdd_post = (const float*)d_in[15];
  const float* kdd_post = (const float*)d_in[16];
  float* out = (float*)d_out;

  // workspace layout: logits WS (37,748,736 B) | kb (8,388,608 B) | vT (8,454,144 B)
  float*  wsLog = (float*)d_ws;
  ushort* kb = (ushort*)((char*)d_ws + 37748736ll);
  ushort* vT = (ushort*)((char*)d_ws + 46137344ll);

  conv_k<<<2048, 256, 0, stream>>>(k, kb);           // 2048*256*8 = 4,194,304 elems
  trans_v<<<4096, 256, 0, stream>>>(v, vT);          // 2*16*4*32 tiles
  attn_main<<<256, 512, 0, stream>>>(
      q, w_pre, w_post,
      qw1_pre, qw2_pre, kw1_pre, kw2_pre,
      qw1_post, qw2_post, kw1_post, kw2_post,
      qdd_pre, kdd_pre, qdd_post, kdd_post,
      kb, vT, wsLog, out);
}